// Round 1
// 365.328 us; speedup vs baseline: 1.1051x; 1.1051x over previous
//
#include <hip/hip_runtime.h>

#define BB 8
#define SS 1024
#define HH 768
#define EE 9
#define DD 64
#define NCOL (EE * 2 * DD)  // 1152

typedef __bf16 bf16x8 __attribute__((ext_vector_type(8)));
typedef float f32x4 __attribute__((ext_vector_type(4)));

__device__ __forceinline__ unsigned short f2b(float f) {
    unsigned int x = __float_as_uint(f);
    unsigned int r = (x + 0x7fffu + ((x >> 16) & 1u)) >> 16;
    return (unsigned short)r;
}

__device__ __forceinline__ void gload_lds16(const void* g, void* l) {
    __builtin_amdgcn_global_load_lds(
        (const __attribute__((address_space(1))) void*)g,
        (__attribute__((address_space(3))) void*)l, 16, 0, 0);
}

// ---------------------------------------------------------------------------
// Kernel 0: f32 -> bf16 (RNE), vectorized. Removes the per-tile conversion
// redundancy (lhs was converted 9x, W 64x inside the old GEMM loop).
// ---------------------------------------------------------------------------
__global__ __launch_bounds__(256) void to_bf16(const float* __restrict__ in,
                                               unsigned short* __restrict__ out,
                                               int n4) {
    int i = blockIdx.x * 256 + threadIdx.x;
    if (i >= n4) return;
    float4 v = ((const float4*)in)[i];
    ushort4 o = {f2b(v.x), f2b(v.y), f2b(v.z), f2b(v.w)};
    ((ushort4*)out)[i] = o;
}

// ---------------------------------------------------------------------------
// Kernel 1: C = A @ W^T + bias, RoPE, write q/k bf16 to ws [b*E+e][s][d].
// m97 structure: 128x128 tile, BK=32, bf16 inputs staged with
// global_load_lds width=16 into linear LDS; 8x ds_read_b128 + 16 MFMA per
// wave per K-step. 4 waves in 2x2; wave N-span = 64 = one (e, q/k) group, so
// the rotate-half partner (d +/- 32) is acc tile nt +/- 2, same lane & reg.
// ---------------------------------------------------------------------------
__global__ __launch_bounds__(256) void dense_rope_mfma(
    const unsigned short* __restrict__ Abf,  // [8192][768] bf16
    const unsigned short* __restrict__ Wbf,  // [1152][768] bf16
    const float* __restrict__ bias,          // [1152]
    unsigned short* __restrict__ q_ws,
    unsigned short* __restrict__ k_ws) {
    __shared__ unsigned short As[128 * 32];  // linear: gload_lds needs it
    __shared__ unsigned short Bs[128 * 32];

    const int t = threadIdx.x;
    const int lane = t & 63, wave = t >> 6;
    const int quad = lane >> 4, lr = lane & 15;
    const int wm = wave >> 1, wn = wave & 1;
    const int j0 = blockIdx.x * 128;  // x-major over N: consecutive blocks reuse A in L2
    const int m0 = blockIdx.y * 128;

    f32x4 acc[4][4] = {};

    // Staging decomposition: 128x32 bf16 tile = 8 KB = 512 x 16B chunks.
    // chunk = i*256 + wave*64 + lane; LDS dest base (wave-uniform) + lane*16.
    const int srow = wave * 16 + (lane >> 2);   // + i*64
    const int sc8 = (lane & 3) * 8;

    for (int kt = 0; kt < HH / 32; ++kt) {
        const int k0 = kt * 32;
        __syncthreads();  // previous tile's LDS fully consumed
#pragma unroll
        for (int i = 0; i < 2; ++i) {
            const int row = i * 64 + srow;
            const int lb = i * 2048 + wave * 512;  // ushort offset of chunk base
            gload_lds16(&Abf[(size_t)(m0 + row) * HH + k0 + sc8], &As[lb]);
            gload_lds16(&Wbf[(size_t)(j0 + row) * HH + k0 + sc8], &Bs[lb]);
        }
        __syncthreads();  // drains vmcnt(0): staged tile visible

        bf16x8 af[4], bf[4];
#pragma unroll
        for (int mt = 0; mt < 4; ++mt)
            af[mt] = *(const bf16x8*)&As[(wm * 64 + mt * 16 + lr) * 32 + quad * 8];
#pragma unroll
        for (int nt = 0; nt < 4; ++nt)
            bf[nt] = *(const bf16x8*)&Bs[(wn * 64 + nt * 16 + lr) * 32 + quad * 8];
#pragma unroll
        for (int mt = 0; mt < 4; ++mt)
#pragma unroll
            for (int nt = 0; nt < 4; ++nt)
                acc[mt][nt] = __builtin_amdgcn_mfma_f32_16x16x32_bf16(
                    af[mt], bf[nt], acc[mt][nt], 0, 0, 0);
    }

    // Epilogue: bias + RoPE entirely in registers, store bf16.
    const int gcol0 = j0 + wn * 64;       // aligned 64-col group
    const int g = gcol0 >> 6;
    const int e = g >> 1;
    unsigned short* dst = (g & 1) ? k_ws : q_ws;
    const int b_idx = m0 >> 10;           // 128 | 1024, uniform per block
    const size_t zbase = (size_t)(b_idx * EE + e) * SS;
    const float L2_1E4_D32 = 0.4152410118609203f;  // log2(10000)/32

    float bb[4], invf[4];
#pragma unroll
    for (int nt = 0; nt < 4; ++nt) {
        bb[nt] = bias[gcol0 + nt * 16 + lr];
        int half = (nt * 16 + lr) >> 1;
        invf[nt] = exp2f(-(float)half * L2_1E4_D32);
    }
    const int s0 = (m0 & (SS - 1)) + wm * 64;
#pragma unroll
    for (int mt = 0; mt < 4; ++mt) {
#pragma unroll
        for (int reg = 0; reg < 4; ++reg) {
            const int s = s0 + mt * 16 + quad * 4 + reg;
            float c[4];
#pragma unroll
            for (int nt = 0; nt < 4; ++nt) c[nt] = acc[mt][nt][reg] + bb[nt];
#pragma unroll
            for (int nt = 0; nt < 4; ++nt) {
                float rot = (nt < 2) ? -c[nt + 2] : c[nt - 2];
                float ang = (float)s * invf[nt];
                float sv, cv;
                __sincosf(ang, &sv, &cv);
                const int d = nt * 16 + lr;
                dst[(zbase + s) * DD + d] = f2b(c[nt] * cv + rot * sv);
            }
        }
    }
}

// ---------------------------------------------------------------------------
// Kernel 2: logits[z][m][n] = dot(q[z][m], k[z][n]) / 8, pad + causal mask.
// 128x128 tile per block, K=64 staged once (2 MFMA k-steps), direct stores.
// ---------------------------------------------------------------------------
#define LDA2 72  // 64 + 8 pad; row stride 144 B, 16B-aligned
__global__ __launch_bounds__(256) void logits_mfma(
    const unsigned short* __restrict__ q_ws,
    const unsigned short* __restrict__ k_ws,
    const float* __restrict__ mask,  // [B][S]
    float* __restrict__ out) {       // [B*E][S][S]
    __shared__ unsigned short Qs[128 * LDA2];
    __shared__ unsigned short Ks[128 * LDA2];

    const int t = threadIdx.x;
    const int lane = t & 63, wave = t >> 6;
    const int quad = lane >> 4, lr = lane & 15;
    const int wm = wave >> 1, wn = wave & 1;
    const int n0 = blockIdx.x * 128;
    const int m0 = blockIdx.y * 128;
    const int z = blockIdx.z;        // b*E + e
    const int b_idx = z / EE;

    const uint4* qsrc = (const uint4*)(q_ws + ((size_t)z * SS + m0) * DD);
    const uint4* ksrc = (const uint4*)(k_ws + ((size_t)z * SS + n0) * DD);
#pragma unroll
    for (int i = 0; i < 4; ++i) {
        int idx = t + i * 256;       // 1024 16B chunks per 128x64 bf16 tile
        int row = idx >> 3, c8 = (idx & 7) * 8;
        uint4 qv = qsrc[idx];
        uint4 kv = ksrc[idx];
        *(uint4*)&Qs[row * LDA2 + c8] = qv;
        *(uint4*)&Ks[row * LDA2 + c8] = kv;
    }
    __syncthreads();

    f32x4 acc[4][4] = {};
#pragma unroll
    for (int ks = 0; ks < DD; ks += 32) {
        bf16x8 af[4], bf[4];
#pragma unroll
        for (int mt = 0; mt < 4; ++mt)
            af[mt] = *(const bf16x8*)&Qs[(wm * 64 + mt * 16 + lr) * LDA2 + ks + quad * 8];
#pragma unroll
        for (int nt = 0; nt < 4; ++nt)
            bf[nt] = *(const bf16x8*)&Ks[(wn * 64 + nt * 16 + lr) * LDA2 + ks + quad * 8];
#pragma unroll
        for (int mt = 0; mt < 4; ++mt)
#pragma unroll
            for (int nt = 0; nt < 4; ++nt)
                acc[mt][nt] = __builtin_amdgcn_mfma_f32_16x16x32_bf16(
                    af[mt], bf[nt], acc[mt][nt], 0, 0, 0);
    }

    float p[4];
#pragma unroll
    for (int nt = 0; nt < 4; ++nt)
        p[nt] = mask[b_idx * SS + n0 + wn * 64 + nt * 16 + lr];

    float* outz = out + (size_t)z * SS * SS;
#pragma unroll
    for (int mt = 0; mt < 4; ++mt) {
#pragma unroll
        for (int reg = 0; reg < 4; ++reg) {
            const int m = m0 + wm * 64 + mt * 16 + quad * 4 + reg;
#pragma unroll
            for (int nt = 0; nt < 4; ++nt) {
                const int n = n0 + wn * 64 + nt * 16 + lr;
                float v = acc[mt][nt][reg] * 0.125f;
                v = v * p[nt] - (1.0f - p[nt]) * 10000.0f;
                if (n < m) v -= 10000.0f;
                outz[(size_t)m * SS + n] = v;
            }
        }
    }
}

extern "C" void kernel_launch(void* const* d_in, const int* in_sizes, int n_in,
                              void* d_out, int out_size, void* d_ws, size_t ws_size,
                              hipStream_t stream) {
    const float* lhs  = (const float*)d_in[0];  // [8][1024][768]
    const float* mask = (const float*)d_in[1];  // [8][1024]
    const float* W    = (const float*)d_in[2];  // [1152][768]
    const float* bias = (const float*)d_in[3];  // [1152]
    float* out = (float*)d_out;                 // [8][9][1024][1024]

    unsigned short* q_ws = (unsigned short*)d_ws;
    unsigned short* k_ws = q_ws + (size_t)BB * EE * SS * DD;   // 4,718,592 each
    unsigned short* Abf  = k_ws + (size_t)BB * EE * SS * DD;   // [8192][768] bf16
    unsigned short* Wbf  = Abf + (size_t)BB * SS * HH;         // [1152][768] bf16

    to_bf16<<<(BB * SS * HH) / 4 / 256, 256, 0, stream>>>(lhs, Abf, (BB * SS * HH) / 4);
    to_bf16<<<(NCOL * HH) / 4 / 256, 256, 0, stream>>>(W, Wbf, (NCOL * HH) / 4);

    dim3 g1(NCOL / 128, (BB * SS) / 128);  // 9 x 64
    dense_rope_mfma<<<g1, 256, 0, stream>>>(Abf, Wbf, bias, q_ws, k_ws);

    dim3 g2(SS / 128, SS / 128, BB * EE);  // 8 x 8 x 72
    logits_mfma<<<g2, 256, 0, stream>>>(q_ws, k_ws, mask, out);
}